// Round 8
// baseline (284.849 us; speedup 1.0000x reference)
//
#include <hip/hip_runtime.h>
#include <stdint.h>

#define NN 20000
#define NE 200000
#define NG 128
#define NJOBS 3125
#define SLOTS 1024   // (512/2 blocks per half) * 4 waves

typedef __attribute__((ext_vector_type(8))) short short8;
typedef __attribute__((ext_vector_type(4))) float f32x4;
typedef __attribute__((ext_vector_type(8))) _Float16 half8;
typedef __attribute__((ext_vector_type(2))) _Float16 half2v;
typedef __attribute__((ext_vector_type(2))) __fp16   pk16;   // cvt_pkrtz result type

static __device__ __forceinline__ float bf2f(short s) {
    union { unsigned int u; float f; } x;
    x.u = ((unsigned int)(unsigned short)s) << 16;
    return x.f;
}
static __device__ __forceinline__ unsigned short f2bf(float f) {
    unsigned int u = __builtin_bit_cast(unsigned int, f);
    u += 0x7fffu + ((u >> 16) & 1u);
    return (unsigned short)(u >> 16);
}
static __device__ __forceinline__ unsigned short f2h(float f) {
    _Float16 h = (_Float16)f;
    return __builtin_bit_cast(unsigned short, h);
}
// per-wave dtype detect (bf16 low-short exponent-field statistics)
static __device__ __forceinline__ int detect_isbf(const unsigned int* x) {
    unsigned int u = x[threadIdx.x & 63];
    unsigned int el = (u >> 7) & 0xffu;
    unsigned long long bm = __ballot((el >= 100u) && (el <= 140u));
    return __popcll(bm) > 32;
}

// ------------------------------------------------------------------ pre (fused):
// blocks [0,264): W2T f16 [32][1056]; block 1 extra: w1t (f16) / b1f (f32);
// blocks [264,2764): node embed; [2764,3155): dst histogram (cnt pre-zeroed
// by hipMemsetAsync -- no intra-dispatch ordering dependency).
__global__ __launch_bounds__(256) void k_pre(
    const void* w2a, const void* b2a, const void* w2b, const void* b2b,
    const void* w1a, const void* b1a, const void* w1b, const void* b1b,
    const void* x, const void* nw, const void* nb, const int* __restrict__ dst,
    short* __restrict__ W2Ta, short* __restrict__ W2Tb,
    short* __restrict__ w1t_ws, float* __restrict__ b1f_ws,
    int* __restrict__ cnt, float* __restrict__ h0) {
    const int bid = blockIdx.x;
    if (bid < 264) {
        const int isbf = detect_isbf((const unsigned int*)x);
        if (bid == 1) {
            for (int i = threadIdx.x; i < 1024; i += 256) {
                int layer = i >> 9, jj = i & 511, c = jj >> 4, q = jj & 15;
                const void* w1p = layer ? w1b : w1a;
                float v = isbf ? bf2f(((const short*)w1p)[q * 32 + c])
                               : ((const float*)w1p)[q * 32 + c];
                w1t_ws[i] = (short)f2h(v);
            }
            for (int i = threadIdx.x; i < 64; i += 256) {
                int layer = i >> 5, c = i & 31;
                const void* b1p = layer ? b1b : b1a;
                b1f_ws[i] = isbf ? bf2f(((const short*)b1p)[c])
                                 : ((const float*)b1p)[c];
            }
        }
        int t = bid * 256 + threadIdx.x;
        if (t >= 2 * 32 * 1056) return;
        int layer = t / (32 * 1056);
        int r = t - layer * (32 * 1056);
        int o = r / 1056, kp = r - o * 1056;
        const void* w2 = layer ? w2b : w2a;
        const void* b2 = layer ? b2b : b2a;
        int idx; const void* sp;
        if (kp < 1024) { int kk = kp >> 5, i = kp & 31; idx = kk * 1024 + i * 32 + o; sp = w2; }
        else           { int i = kp - 1024;             idx = i * 32 + o;             sp = b2; }
        float v = isbf ? bf2f(((const short*)sp)[idx]) : ((const float*)sp)[idx];
        (layer ? W2Tb : W2Ta)[o * 1056 + kp] = (short)f2h(v);
        return;
    }
    if (bid < 2764) {
        const int isbf = detect_isbf((const unsigned int*)x);
        __shared__ float wf[64 * 32];
        __shared__ float bfs[32];
        for (int i = threadIdx.x; i < 64 * 32; i += 256)
            wf[i] = isbf ? bf2f(((const short*)nw)[i]) : ((const float*)nw)[i];
        if (threadIdx.x < 32)
            bfs[threadIdx.x] = isbf ? bf2f(((const short*)nb)[threadIdx.x])
                                    : ((const float*)nb)[threadIdx.x];
        __syncthreads();
        int t = (bid - 264) * 256 + threadIdx.x;
        int v = t >> 5, c = t & 31;
        float acc = bfs[c];
        if (isbf) {
            const short* xr = (const short*)x + v * 64;
#pragma unroll
            for (int q = 0; q < 64; ++q) acc += bf2f(xr[q]) * wf[q * 32 + c];
        } else {
            const float* xr = (const float*)x + v * 64;
#pragma unroll
            for (int q = 0; q < 64; ++q) acc += xr[q] * wf[q * 32 + c];
        }
        h0[t] = acc > 0.f ? acc : 0.01f * acc;
        return;
    }
    int e = (bid - 2764) * 512 + threadIdx.x;
    if (e < NE) atomicAdd(&cnt[dst[e]], 1);
    e += 256;
    if (e < NE) atomicAdd(&cnt[dst[e]], 1);
}

// ------------------------------------------------------------------ scan (1 block):
// exclusive prefix over cnt[20000] -> row_ptr[20001] + ptr_work copy; zero pooled
__global__ __launch_bounds__(1024) void k_scan(
    const int* __restrict__ cnt, int* __restrict__ row_ptr,
    int* __restrict__ ptr_work, float* __restrict__ pooled) {
    __shared__ int part[1024];
    const int t = threadIdx.x;
    for (int i = t; i < NG * 32; i += 1024) pooled[i] = 0.f;
    int loc[20];
    int s = 0;
    const int base = t * 20;
#pragma unroll
    for (int i = 0; i < 20; ++i) {
        loc[i] = s;
        int idx = base + i;
        s += (idx < NN) ? cnt[idx] : 0;
    }
    part[t] = s;
    __syncthreads();
    for (int off = 1; off < 1024; off <<= 1) {
        int v = (t >= off) ? part[t - off] : 0;
        __syncthreads();
        part[t] += v;
        __syncthreads();
    }
    int excl = part[t] - s;
#pragma unroll
    for (int i = 0; i < 20; ++i) {
        int idx = base + i;
        if (idx <= NN) {
            int v = excl + loc[i];
            row_ptr[idx] = v;
            if (idx < NN) ptr_work[idx] = v;
        }
    }
}

// ------------------------------------------------------------------ scatter:
// sorted position p = ptr_work[dst[e]]++; src_s[p]=src[e]; ea_s[p]= f16 row
__global__ __launch_bounds__(256) void k_scatter(
    const int* __restrict__ src, const int* __restrict__ dst,
    const void* ea, int* __restrict__ ptr_work,
    int* __restrict__ src_s, short* __restrict__ ea_s) {
    const int isbf = detect_isbf((const unsigned int*)ea);
    int e = blockIdx.x * 256 + threadIdx.x;
    if (e >= NE) return;
    int d = dst[e];
    int p = atomicAdd(&ptr_work[d], 1);
    src_s[p] = src[e];
    union { unsigned short us[16]; short8 v[2]; } o16;
    if (isbf) {
        const short* q = (const short*)ea + (size_t)e * 16;
#pragma unroll
        for (int i = 0; i < 16; ++i) o16.us[i] = f2h(bf2f(q[i]));
    } else {
        const float* q = (const float*)ea + (size_t)e * 16;
#pragma unroll
        for (int i = 0; i < 16; ++i) o16.us[i] = f2h(q[i]);
    }
    *(short8*)&ea_s[(size_t)p * 16] = o16.v[0];
    *(short8*)&ea_s[(size_t)p * 16 + 8] = o16.v[1];
}

// ------------------------------------------------------------------ edge kernel:
// msg = P @ W2' over sorted edges; K split in halves (blockIdx&1); all W2'
// fragments held in REGISTERS (job-invariant); h1 fp32 in LDS; f16 MFMA.
__global__ __launch_bounds__(256, 2) void k_edge(
    const float* __restrict__ h_in,   // [N,32] fp32
    const short* __restrict__ W2T,    // f16 bits [32][1056]
    const short* __restrict__ w1pre,  // f16 bits [32][16] transposed
    const float* __restrict__ b1pre,  // [32] fp32
    const int* __restrict__ src_s,    // [E] sorted
    const short* __restrict__ ea_s,   // [E][16] f16 sorted
    unsigned int* __restrict__ msgA, unsigned int* __restrict__ msgB) {
    __shared__ __align__(16) float h1s[4 * 64 * 20];  // per-wave [64][20] fp32

    const int half = blockIdx.x & 1;
    const int k0   = half ? 512 : 0;
    const int S    = half ? 17 : 16;
    unsigned int* __restrict__ msg_out = half ? msgB : msgA;

    const int lane = threadIdx.x & 63;
    const int wid  = threadIdx.x >> 6;
    const int m    = lane & 15;
    const int quad = lane >> 4;
    float* h1w = h1s + wid * (64 * 20);

    // ---- job-invariant weight fragments -> registers (L2-hot after blk 0) ----
    half8 wf0[17], wf1[17];
#pragma unroll 17
    for (int s = 0; s < 17; ++s) {
        if (s < S) {
            wf0[s] = __builtin_bit_cast(half8,
                *(const short8*)&W2T[m * 1056 + k0 + (s << 5) + (quad << 3)]);
            wf1[s] = __builtin_bit_cast(half8,
                *(const short8*)&W2T[(m + 16) * 1056 + k0 + (s << 5) + (quad << 3)]);
        }
    }
    half8 w1frag = (half8)0;
    if (quad < 2) {
        int c = m + (half << 4);
        w1frag = __builtin_bit_cast(half8, *(const short8*)&w1pre[c * 16 + ((quad & 1) << 3)]);
    }
    const float b1v = b1pre[m + (half << 4)];
    const f32x4 zero4 = {0.f, 0.f, 0.f, 0.f};

    int j = (blockIdx.x >> 1) * 4 + wid;  // slot in [0,1024)

    // ---- prologue: job j inputs + src for j+SLOTS ----
    half8 eafc[4];
    f32x4 hs[4][2];
    int srcn[4];
    {
        const int e0 = j << 6;
        int s0[4];
#pragma unroll
        for (int mt = 0; mt < 4; ++mt) {
            eafc[mt] = __builtin_bit_cast(half8,
                *(const short8*)&ea_s[(size_t)(e0 + mt * 16 + m) * 16 + ((quad & 1) << 3)]);
            s0[mt] = src_s[e0 + mt * 16 + m];
        }
#pragma unroll
        for (int mt = 0; mt < 4; ++mt) {
            const float* hr = h_in + (size_t)s0[mt] * 32 + (quad << 3);
            hs[mt][0] = *(const f32x4*)hr;
            hs[mt][1] = *(const f32x4*)(hr + 4);
        }
        const int en = (j + SLOTS) << 6;
#pragma unroll
        for (int mt = 0; mt < 4; ++mt) srcn[mt] = src_s[en + mt * 16 + m];
    }

    while (j < NJOBS) {
        const int e0 = j << 6;
        const int jn = j + SLOTS;

        // ---- phase 1: h1 = relu(ea@w1+b1) -> fp32 in LDS ----
#pragma unroll
        for (int mt = 0; mt < 4; ++mt) {
            half8 eaq = (quad < 2) ? eafc[mt] : (half8)0;
            f32x4 hacc = __builtin_amdgcn_mfma_f32_16x16x32_f16(
                eaq, w1frag, zero4, 0, 0, 0);
#pragma unroll
            for (int r = 0; r < 4; ++r) {
                float v = hacc[r] + b1v;
                v = v > 0.f ? v : 0.f;
                h1w[(mt * 16 + quad * 4 + r) * 20 + m] = v;
            }
        }
        if (half) h1w[lane * 20 + 16] = 1.0f;  // bias row, scale 1.0
        __asm volatile("s_waitcnt lgkmcnt(0)" ::: "memory");

        // prefetch next job's ea
        if (jn < NJOBS) {
            const int en = jn << 6;
#pragma unroll
            for (int mt = 0; mt < 4; ++mt)
                eafc[mt] = __builtin_bit_cast(half8,
                    *(const short8*)&ea_s[(size_t)(en + mt * 16 + m) * 16 + ((quad & 1) << 3)]);
        }

        // ---- phase 2: K loop, weights from registers ----
        f32x4 acc0[4], acc1[4];
#pragma unroll
        for (int mt = 0; mt < 4; ++mt) { acc0[mt] = zero4; acc1[mt] = zero4; }

#pragma unroll
        for (int c = 0; c < 4; ++c) {
            f32x4 h4[4];
#pragma unroll
            for (int mt = 0; mt < 4; ++mt)
                h4[mt] = *(const f32x4*)&h1w[(mt * 16 + m) * 20 + (c << 2)];
#pragma unroll
            for (int u = 0; u < 4; ++u) {
                const int s = (c << 2) + u;
#pragma unroll
                for (int mt = 0; mt < 4; ++mt) {
                    float sc = h4[mt][u];
                    union { pk16 h2[4]; half8 v; } a;
#pragma unroll
                    for (int p = 0; p < 4; ++p) {
                        f32x4 hv = hs[mt][p >> 1];
                        a.h2[p] = __builtin_amdgcn_cvt_pkrtz(sc * hv[(p & 1) * 2],
                                                             sc * hv[(p & 1) * 2 + 1]);
                    }
                    acc0[mt] = __builtin_amdgcn_mfma_f32_16x16x32_f16(a.v, wf0[s], acc0[mt], 0, 0, 0);
                    acc1[mt] = __builtin_amdgcn_mfma_f32_16x16x32_f16(a.v, wf1[s], acc1[mt], 0, 0, 0);
                }
            }
        }
        if (half) {  // tail step s=16 (bias rows)
#pragma unroll
            for (int mt = 0; mt < 4; ++mt) {
                float sc = h1w[(mt * 16 + m) * 20 + 16];
                union { pk16 h2[4]; half8 v; } a;
#pragma unroll
                for (int p = 0; p < 4; ++p) {
                    f32x4 hv = hs[mt][p >> 1];
                    a.h2[p] = __builtin_amdgcn_cvt_pkrtz(sc * hv[(p & 1) * 2],
                                                         sc * hv[(p & 1) * 2 + 1]);
                }
                acc0[mt] = __builtin_amdgcn_mfma_f32_16x16x32_f16(a.v, wf0[16], acc0[mt], 0, 0, 0);
                acc1[mt] = __builtin_amdgcn_mfma_f32_16x16x32_f16(a.v, wf1[16], acc1[mt], 0, 0, 0);
            }
        }

        // prefetch next job's hsrc + src for j+2*SLOTS
        if (jn < NJOBS) {
#pragma unroll
            for (int mt = 0; mt < 4; ++mt) {
                const float* hr = h_in + (size_t)srcn[mt] * 32 + (quad << 3);
                hs[mt][0] = *(const f32x4*)hr;
                hs[mt][1] = *(const f32x4*)(hr + 4);
            }
            const int jn2 = jn + SLOTS;
            if (jn2 < NJOBS) {
                const int en2 = jn2 << 6;
#pragma unroll
                for (int mt = 0; mt < 4; ++mt) srcn[mt] = src_s[en2 + mt * 16 + m];
            }
        }

        // ---- epilogue: packed-f16 stores (cols m, m+16 per dword) ----
#pragma unroll
        for (int mt = 0; mt < 4; ++mt) {
#pragma unroll
            for (int r = 0; r < 4; ++r) {
                pk16 pk = __builtin_amdgcn_cvt_pkrtz(acc0[mt][r], acc1[mt][r]);
                msg_out[(size_t)(e0 + mt * 16 + quad * 4 + r) * 16 + m] =
                    __builtin_bit_cast(unsigned int, pk);
            }
        }
        j = jn;
    }
}

// ------------------------------------------------------------------ aggregate:
// acc = h_prev@root + bias + sum(msgA+msgB rows) per dst; lrelu.
// mode 0: write h1b.  mode 1: write atom_embs + pooled atomics.
__global__ __launch_bounds__(256) void k_agg(
    const unsigned int* __restrict__ msgA, const unsigned int* __restrict__ msgB,
    const int* __restrict__ row_ptr, const float* __restrict__ h_prev,
    const void* root, const void* bias, const unsigned int* xdet,
    const int* __restrict__ batch, int mode,
    float* __restrict__ h1b, void* __restrict__ out, float* pooled) {
    const int isbf = detect_isbf(xdet);
    __shared__ float rf[32 * 32];
    __shared__ float bfs[32];
    for (int i = threadIdx.x; i < 1024; i += 256)
        rf[i] = isbf ? bf2f(((const short*)root)[i]) : ((const float*)root)[i];
    if (threadIdx.x < 32)
        bfs[threadIdx.x] = isbf ? bf2f(((const short*)bias)[threadIdx.x])
                                : ((const float*)bias)[threadIdx.x];
    __syncthreads();
    int t = blockIdx.x * 256 + threadIdx.x;
    if (t >= NN * 32) return;
    int d = t >> 5, c = t & 31;
    const float* hr = h_prev + (size_t)d * 32;
    float acc = bfs[c];
#pragma unroll
    for (int q = 0; q < 32; ++q) acc += hr[q] * rf[q * 32 + c];
    const int b0 = row_ptr[d], b1 = row_ptr[d + 1];
    const int ci = c & 15;
    const int hi = c >> 4;
    float s = 0.f;
    for (int e = b0; e < b1; ++e) {
        half2v ha = __builtin_bit_cast(half2v, msgA[(size_t)e * 16 + ci]);
        half2v hb = __builtin_bit_cast(half2v, msgB[(size_t)e * 16 + ci]);
        s += (float)ha[hi] + (float)hb[hi];
    }
    float v = acc + s;
    v = v > 0.f ? v : 0.01f * v;
    if (mode == 0) {
        h1b[t] = v;
    } else {
        if (isbf) ((short*)out)[4096 + t] = (short)f2bf(v);
        else      ((float*)out)[4096 + t] = v;
        atomicAdd(&pooled[batch[d] * 32 + c], v);
    }
}

// ------------------------------------------------------------------ graph head
__global__ __launch_bounds__(64) void k_graph_out(
    const float* __restrict__ pooled, const void* fcw, const void* fcb,
    const unsigned int* xdet, void* __restrict__ out) {
    const int isbf = detect_isbf(xdet);
    int g = blockIdx.x;
    int t = threadIdx.x;
    __shared__ float pn[32];
    if (t < 32) {
        float p = pooled[g * 32 + t];
        float sq = p * p;
#pragma unroll
        for (int o = 16; o > 0; o >>= 1) sq += __shfl_xor(sq, o, 64);
        float inv = 1.0f / fmaxf(sqrtf(sq), 1e-12f);
        pn[t] = p * inv;
    }
    __syncthreads();
    if (t < 32) {
        float acc = isbf ? bf2f(((const short*)fcb)[t]) : ((const float*)fcb)[t];
#pragma unroll
        for (int q = 0; q < 32; ++q) {
            float wv = isbf ? bf2f(((const short*)fcw)[q * 32 + t])
                            : ((const float*)fcw)[q * 32 + t];
            acc += pn[q] * wv;
        }
        if (isbf) ((short*)out)[g * 32 + t] = (short)f2bf(acc);
        else      ((float*)out)[g * 32 + t] = acc;
    }
}

extern "C" void kernel_launch(void* const* d_in, const int* in_sizes, int n_in,
                              void* d_out, int out_size, void* d_ws, size_t ws_size,
                              hipStream_t stream) {
    (void)in_sizes; (void)n_in; (void)out_size; (void)ws_size;
    const void* x     = d_in[0];
    const int*  eidx  = (const int*)d_in[1];
    const void* ea    = d_in[2];
    const int*  batch = (const int*)d_in[3];
    const void* nfcw  = d_in[5];
    const void* nfcb  = d_in[6];
    const void* e1w1  = d_in[7];
    const void* e1b1  = d_in[8];
    const void* e1w2  = d_in[9];
    const void* e1b2  = d_in[10];
    const void* root1 = d_in[11];
    const void* bias1 = d_in[12];
    const void* e2w1  = d_in[13];
    const void* e2b1  = d_in[14];
    const void* e2w2  = d_in[15];
    const void* e2b2  = d_in[16];
    const void* root2 = d_in[17];
    const void* bias2 = d_in[18];
    const void* fcw   = d_in[19];
    const void* fcb   = d_in[20];
    const unsigned int* xdet = (const unsigned int*)x;

    char* ws = (char*)d_ws;
    float* h0     = (float*)ws;        ws += (size_t)NN * 32 * 4;
    float* h1b    = (float*)ws;        ws += (size_t)NN * 32 * 4;
    unsigned int* msgA = (unsigned int*)ws; ws += (size_t)NE * 16 * 4;
    unsigned int* msgB = (unsigned int*)ws; ws += (size_t)NE * 16 * 4;
    short* ea_s   = (short*)ws;        ws += (size_t)NE * 16 * 2;
    int*   src_s  = (int*)ws;          ws += (size_t)NE * 4;
    short* W2T1   = (short*)ws;        ws += 32 * 1056 * 2;
    short* W2T2   = (short*)ws;        ws += 32 * 1056 * 2;
    short* w1t_ws = (short*)ws;        ws += 1024 * 2;
    float* b1f_ws = (float*)ws;        ws += 64 * 4;
    int*   cnt    = (int*)ws;          ws += (size_t)NN * 4;
    int*   row_ptr= (int*)ws;          ws += (size_t)(NN + 8) * 4;
    int*   ptr_wk = (int*)ws;          ws += (size_t)NN * 4;
    float* pooled = (float*)ws;        ws += NG * 32 * 4;

    const int* srcp = eidx;
    const int* dstp = eidx + NE;

    // 0: zero the histogram buffer (graph-capture-legal stream memset;
    //    MUST be a separate stream op -- intra-kernel zeroing raced in R7)
    hipMemsetAsync(cnt, 0, (size_t)NN * 4, stream);
    // 1: fused prep + node embed + dst histogram
    k_pre<<<3155, 256, 0, stream>>>(
        e1w2, e1b2, e2w2, e2b2, e1w1, e1b1, e2w1, e2b1,
        x, nfcw, nfcb, dstp,
        W2T1, W2T2, w1t_ws, b1f_ws, cnt, h0);
    // 2: prefix scan -> row_ptr, ptr_work; zero pooled
    k_scan<<<1, 1024, 0, stream>>>(cnt, row_ptr, ptr_wk, pooled);
    // 3: counting-sort scatter
    k_scatter<<<(NE + 255) / 256, 256, 0, stream>>>(srcp, dstp, ea, ptr_wk, src_s, ea_s);
    // 4-5: layer 1
    k_edge<<<512, 256, 0, stream>>>(h0, W2T1, w1t_ws, b1f_ws, src_s, ea_s, msgA, msgB);
    k_agg<<<2500, 256, 0, stream>>>(msgA, msgB, row_ptr, h0, root1, bias1, xdet,
                                    batch, 0, h1b, d_out, pooled);
    // 6-7: layer 2
    k_edge<<<512, 256, 0, stream>>>(h1b, W2T2, w1t_ws + 512, b1f_ws + 32, src_s, ea_s, msgA, msgB);
    k_agg<<<2500, 256, 0, stream>>>(msgA, msgB, row_ptr, h1b, root2, bias2, xdet,
                                    batch, 1, h1b, d_out, pooled);
    // 8: graph head
    k_graph_out<<<NG, 64, 0, stream>>>(pooled, fcw, fcb, xdet, d_out);
}